// Round 16
// baseline (2307.487 us; speedup 1.0000x reference)
//
#include <hip/hip_runtime.h>

#define BB 128
#define TT 2048
#define HH 64

typedef float2 f2;
struct f2x2 { f2 lo, hi; };

__device__ __forceinline__ float sigm(float v) {
    return __builtin_amdgcn_rcpf(1.0f + __expf(-v));
}
__device__ __forceinline__ float ftanh(float v) {
    float e = __expf(-2.0f * fabsf(v));
    float r = (1.0f - e) * __builtin_amdgcn_rcpf(1.0f + e);
    return copysignf(r, v);
}

#define PIN2(v) asm volatile("" : "+v"(v))
// packed fp32 FMA: 1 inst / 2 MACs (VOP3P)
#define PKFMA(acc, w, h) \
    asm("v_pk_fma_f32 %0, %1, %2, %0" : "+v"(acc) : "v"(w), "v"(h))
// split a float4 (4 consecutive VGPRs) into two f2 register pairs, no movs
#define SPLIT(v4, lo_, hi_) \
    { f2x2 u_ = __builtin_bit_cast(f2x2, (v4)); lo_ = u_.lo; hi_ = u_.hi; }

// declare / pin / load 32 named f2 (one 64-col row slice)
#define DECLW(W) f2 W##0,W##1,W##2,W##3,W##4,W##5,W##6,W##7,W##8,W##9,W##10,   \
    W##11,W##12,W##13,W##14,W##15,W##16,W##17,W##18,W##19,W##20,W##21,W##22,   \
    W##23,W##24,W##25,W##26,W##27,W##28,W##29,W##30,W##31
#define PINW(W) PIN2(W##0);PIN2(W##1);PIN2(W##2);PIN2(W##3);PIN2(W##4);        \
    PIN2(W##5);PIN2(W##6);PIN2(W##7);PIN2(W##8);PIN2(W##9);PIN2(W##10);        \
    PIN2(W##11);PIN2(W##12);PIN2(W##13);PIN2(W##14);PIN2(W##15);PIN2(W##16);   \
    PIN2(W##17);PIN2(W##18);PIN2(W##19);PIN2(W##20);PIN2(W##21);PIN2(W##22);   \
    PIN2(W##23);PIN2(W##24);PIN2(W##25);PIN2(W##26);PIN2(W##27);PIN2(W##28);   \
    PIN2(W##29);PIN2(W##30);PIN2(W##31)
#define LDW(P, W) do { float4 v_;                                              \
    v_=(P)[0];  SPLIT(v_, W##0,  W##1);  v_=(P)[1];  SPLIT(v_, W##2,  W##3);   \
    v_=(P)[2];  SPLIT(v_, W##4,  W##5);  v_=(P)[3];  SPLIT(v_, W##6,  W##7);   \
    v_=(P)[4];  SPLIT(v_, W##8,  W##9);  v_=(P)[5];  SPLIT(v_, W##10, W##11);  \
    v_=(P)[6];  SPLIT(v_, W##12, W##13); v_=(P)[7];  SPLIT(v_, W##14, W##15);  \
    v_=(P)[8];  SPLIT(v_, W##16, W##17); v_=(P)[9];  SPLIT(v_, W##18, W##19);  \
    v_=(P)[10]; SPLIT(v_, W##20, W##21); v_=(P)[11]; SPLIT(v_, W##22, W##23);  \
    v_=(P)[12]; SPLIT(v_, W##24, W##25); v_=(P)[13]; SPLIT(v_, W##26, W##27);  \
    v_=(P)[14]; SPLIT(v_, W##28, W##29); v_=(P)[15]; SPLIT(v_, W##30, W##31);  \
} while (0)
#define DOTK(K) PKFMA(aR, wa##K, h##K); PKFMA(aZ, wb##K, h##K); PKFMA(aN, wc##K, h##K)

// One block per batch, THREE waves — one per stage, full-K rows per lane.
// R16 vs R15: waves 6->3, per-lane slice 96->192 floats (96 named f2).
// Eliminates ALL cross-lane machinery: no DPP reduce, no gate redundancy,
// no K-half predicates. Lane j owns gate-rows {j,64+j,128+j} x cols 0..63.
//   w0 (Whh0): h1(i)  = GRU1(h1(i-1), x(i))    [h1b parity]
//   w1 (Wih1): xg(i-1)= Wih1*h1(i-1)+bih1      [xgb4 parity; fc-head flush]
//   w2 (Whh1): h2(i-2)= GRU2(h2(i-3), xg(i-2)) [h2b parity, ring store]
// Residency recipe (R13/R15-proven): named f2 + pk_fma "v" constraints +
// LDS pad >80KB (1-block/CU static target) + waves_per_eu(1,1) -> 512-reg
// budget for the ~280 needed. One barrier per timestep.
__global__ __launch_bounds__(192)
__attribute__((amdgpu_waves_per_eu(1, 1)))
void gru_fused(const float* __restrict__ x,
               const float* __restrict__ Wih0, const float* __restrict__ Whh0,
               const float* __restrict__ bih0, const float* __restrict__ bhh0,
               const float* __restrict__ Wih1, const float* __restrict__ Whh1,
               const float* __restrict__ bih1, const float* __restrict__ bhh1,
               const float* __restrict__ fcw, const float* __restrict__ fcb,
               float* __restrict__ out)
{
    const int t = threadIdx.x;
    const int w = t >> 6;           // wave 0..2 == stage
    const int j = t & 63;           // lane == dim
    const int b = blockIdx.x;

    __shared__ __align__(16) float xs[TT * 2];       // 16 KB input
    __shared__ __align__(16) float h1b[2][HH];       // parity
    __shared__ __align__(16) float h2b[2][HH];       // parity
    __shared__ __align__(16) float4 xgb4[2][HH];     // parity, packed {r,z,n,-}
    __shared__ __align__(16) float fwS[HH];
    __shared__ float ring[256][65];                  // h2 history (pads LDS >80KB
                                                     // on purpose: 1-block/CU target)

    // ---- 192 weight floats as 96 named f2 (3 rows x 64 cols) ----
    const float* Wm = (w == 0) ? Whh0 : (w == 1) ? Wih1 : Whh1;
    const float4* P0 = (const float4*)(Wm + (size_t)(0 * HH + j) * HH);
    const float4* P1 = (const float4*)(Wm + (size_t)(1 * HH + j) * HH);
    const float4* P2 = (const float4*)(Wm + (size_t)(2 * HH + j) * HH);
    DECLW(wa); DECLW(wb); DECLW(wc);
    LDW(P0, wa); LDW(P1, wb); LDW(P2, wc);
    PINW(wa); PINW(wb); PINW(wc);

    // biases (folded per stage; d == j)
    float kb0, kb1, kb2, bi2 = 0.f;
    if (w == 0) {            // r,z: fold bih0+bhh0; n: bhh0 inside r*(), bih0 outside
        kb0 = bhh0[j] + bih0[j];
        kb1 = bhh0[HH + j] + bih0[HH + j];
        kb2 = bhh0[2 * HH + j];
        bi2 = bih0[2 * HH + j];
    } else if (w == 1) {
        kb0 = bih1[j]; kb1 = bih1[HH + j]; kb2 = bih1[2 * HH + j];
    } else {
        kb0 = bhh1[j]; kb1 = bhh1[HH + j]; kb2 = bhh1[2 * HH + j];
    }
    float wi0 = 0, wi1 = 0, wi2 = 0, wi3 = 0, wi4 = 0, wi5 = 0;
    if (w == 0) {
        wi0 = Wih0[j * 2];            wi1 = Wih0[j * 2 + 1];
        wi2 = Wih0[(HH + j) * 2];     wi3 = Wih0[(HH + j) * 2 + 1];
        wi4 = Wih0[(2 * HH + j) * 2]; wi5 = Wih0[(2 * HH + j) * 2 + 1];
    }
    const float fcbv = fcb[0];

    // ---- preload x, zero state ----
    {
        const float4* xp  = (const float4*)(x + (size_t)b * TT * 2);
        float4*       xsp = (float4*)xs;
        for (int i2 = t; i2 < TT * 2 / 4; i2 += 192) xsp[i2] = xp[i2];
    }
    if (t < 2 * HH) { ((float*)h1b)[t] = 0.f; ((float*)h2b)[t] = 0.f; }
    if (t < HH) fwS[t] = fcw[t];

    float hreg = 0.f;   // w0: h1[j]; w2: h2[j]

// One timestep. PC = IDX&1, PP = (IDX-1)&1 as literals; FL only in even steps.
#define STEP(IDX, PC, PP, FL)                                                  \
    {                                                                          \
        __syncthreads();                                                       \
        const int i_ = (IDX);                                                  \
        const bool act = (w == 0) ? (i_ < TT)                                  \
                       : (w == 1) ? (i_ >= 1 && i_ <= TT)                      \
                                  : (i_ >= 2);                                 \
        if (act) {                                                             \
            const float4* hp = (const float4*)((w < 2) ? h1b[PP] : h2b[PP]);   \
            DECLW(h);                                                          \
            LDW(hp, h);                                                        \
            f2 aR = {0.f, 0.f}, aZ = {0.f, 0.f}, aN = {0.f, 0.f};              \
            DOTK(0);  DOTK(1);  DOTK(2);  DOTK(3);                             \
            DOTK(4);  DOTK(5);  DOTK(6);  DOTK(7);                             \
            DOTK(8);  DOTK(9);  DOTK(10); DOTK(11);                            \
            DOTK(12); DOTK(13); DOTK(14); DOTK(15);                            \
            DOTK(16); DOTK(17); DOTK(18); DOTK(19);                            \
            DOTK(20); DOTK(21); DOTK(22); DOTK(23);                            \
            DOTK(24); DOTK(25); DOTK(26); DOTK(27);                            \
            DOTK(28); DOTK(29); DOTK(30); DOTK(31);                            \
            float sr = aR.x + aR.y + kb0;                                      \
            float sz = aZ.x + aZ.y + kb1;                                      \
            float sn = aN.x + aN.y + kb2;                                      \
            if (w == 0) {                                                      \
                f2 xv = *(const f2*)(xs + 2 * i_);                             \
                float rr = sigm (fmaf(wi0, xv.x, fmaf(wi1, xv.y, sr)));        \
                float zz = sigm (fmaf(wi2, xv.x, fmaf(wi3, xv.y, sz)));        \
                float nn = ftanh(fmaf(wi4, xv.x, fmaf(wi5, xv.y, bi2)) + rr * sn); \
                hreg = (1.f - zz) * nn + zz * hreg;                            \
                h1b[PC][j] = hreg;                                             \
            } else if (w == 1) {                                               \
                xgb4[PP][j] = make_float4(sr, sz, sn, 0.f);                    \
            } else {                                                           \
                float4 xg = xgb4[PC][j];                                       \
                float rr = sigm (xg.x + sr);                                   \
                float zz = sigm (xg.y + sz);                                   \
                float nn = ftanh(xg.z + rr * sn);                              \
                hreg = (1.f - zz) * nn + zz * hreg;                            \
                h2b[PC][j] = hreg;                                             \
                ring[(i_ - 2) & 255][j] = hreg;                                \
            }                                                                  \
        }                                                                      \
        if (FL && w == 1 && i_ >= 66 && ((i_ - 66) & 63) == 0) {               \
            const int tt = ((i_ - 66) >> 6) * 64 + j;                          \
            const float* rr2 = ring[tt & 255];                                 \
            float acc0 = 0.f, acc1 = 0.f;                                      \
            _Pragma("unroll")                                                  \
            for (int k = 0; k < 64; k += 2) {                                  \
                acc0 += rr2[k]     * fwS[k];                                   \
                acc1 += rr2[k + 1] * fwS[k + 1];                               \
            }                                                                  \
            out[(size_t)b * TT + tt] = acc0 + acc1 + fcbv;                     \
        }                                                                      \
    }

    for (int ii = 0; ii < TT + 2; ii += 2) {
        STEP(ii,     0, 1, true);     // even step: parity (0,1), flush check
        STEP(ii + 1, 1, 0, false);    // odd  step: parity (1,0)
    }
#undef STEP

    __syncthreads();
    if (w == 1) {                                // final chunk: t = 1984..2047
        const int tt = 31 * 64 + j;
        const float* rr2 = ring[tt & 255];
        float acc0 = 0.f, acc1 = 0.f;
        #pragma unroll
        for (int k = 0; k < 64; k += 2) {
            acc0 += rr2[k]     * fwS[k];
            acc1 += rr2[k + 1] * fwS[k + 1];
        }
        out[(size_t)b * TT + tt] = acc0 + acc1 + fcbv;
    }
}

extern "C" void kernel_launch(void* const* d_in, const int* in_sizes, int n_in,
                              void* d_out, int out_size, void* d_ws, size_t ws_size,
                              hipStream_t stream) {
    const float* x    = (const float*)d_in[0];
    const float* Wih0 = (const float*)d_in[1];
    const float* Whh0 = (const float*)d_in[2];
    const float* bih0 = (const float*)d_in[3];
    const float* bhh0 = (const float*)d_in[4];
    const float* Wih1 = (const float*)d_in[5];
    const float* Whh1 = (const float*)d_in[6];
    const float* bih1 = (const float*)d_in[7];
    const float* bhh1 = (const float*)d_in[8];
    const float* fcw  = (const float*)d_in[9];
    const float* fcb  = (const float*)d_in[10];
    float* out = (float*)d_out;

    gru_fused<<<BB, 192, 0, stream>>>(x, Wih0, Whh0, bih0, bhh0,
                                      Wih1, Whh1, bih1, bhh1, fcw, fcb, out);
}

// Round 17
// 1177.011 us; speedup vs baseline: 1.9605x; 1.9605x over previous
//
#include <hip/hip_runtime.h>

#define BB 128
#define TT 2048
#define HH 64

typedef float2 f2;
struct f2x2 { f2 lo, hi; };

__device__ __forceinline__ float sigm(float v) {
    return __builtin_amdgcn_rcpf(1.0f + __expf(-v));
}
__device__ __forceinline__ float ftanh(float v) {
    float e = __expf(-2.0f * fabsf(v));
    float r = (1.0f - e) * __builtin_amdgcn_rcpf(1.0f + e);
    return copysignf(r, v);
}

#define PIN2(v) asm volatile("" : "+v"(v))
// packed fp32 FMA: 1 inst / 2 MACs (VOP3P)
#define PKFMA(acc, w, h) \
    asm("v_pk_fma_f32 %0, %1, %2, %0" : "+v"(acc) : "v"(w), "v"(h))
// split a float4 (4 consecutive VGPRs) into two f2 register pairs, no movs
#define SPLIT(v4, lo_, hi_) \
    { f2x2 u_ = __builtin_bit_cast(f2x2, (v4)); lo_ = u_.lo; hi_ = u_.hi; }

// + lane^1 via quad_perm DPP (VALU pipe, not LDS)
__device__ __forceinline__ float dppadd1(float v) {
    int s_ = __builtin_bit_cast(int, v);
    int p_ = __builtin_amdgcn_update_dpp(0, s_, 0xB1, 0xF, 0xF, true);
    return v + __builtin_bit_cast(float, p_);
}

// R17 = R15 (6 waves, 96 weight-floats/lane — the proven optimum: R16 showed
// 192 fl/lane spills at VGPR 144, and 36864 weight floats / 96 = 384 lanes =
// 6 waves minimum) + SOFT BARRIER replacing __syncthreads.
//
// Soft barrier: per-wave LDS step counters. Wave at step i spins until
// min(cnt[0..5]) >= i-1 (acquire), works, publishes cnt[w]=i (release).
// Every R15 parity-buffer hazard is exactly "peer completed step i-1":
//   - h1b[(i-1)&1] read by s0/s1 @ i   <- written by s0 @ i-1
//   - h1b[i&1] overwrite by s0 @ i     -> last readers s1 @ i-1
//   - xgb4 write @ i overwrites xg(i-3) -> last readers s2 @ i-1
//   - h2b cross-half + overwrite       -> s2 peers @ i-1
//   - ring flush lag <= 66 << 256 slots
// Monotonic counters + publish-always => deadlock-free by induction.
// The 1-step skew de-aligns the per-step LDS bursts and lets waves overlap
// dependency chains (the ~700 cyc/iter convoy stall R15 showed).
//
// Wave->stage map (wave i -> SIMD i%4):
//   w0(s0,h0) w1(s2,h0) w2(s0,h1) w3(s2,h1) w4(s1,h0) w5(s1,h1)
//   s=0: h1(i)  = GRU1(h1(i-1), x(i))          [h1b parity]
//   s=1: xg(i-1)= Wih1*h1(i-1)+bih1            [xgb4 parity, packed float4]
//   s=2: h2(i-2)= GRU2(h2(i-3), xg(i-2))       [h2b parity, ring store]
// fc head: wave 3 flushes 64 outputs every 64 iters from the 256-slot ring.
__global__ __launch_bounds__(384)
__attribute__((amdgpu_waves_per_eu(1, 2)))
void gru_fused(const float* __restrict__ x,
               const float* __restrict__ Wih0, const float* __restrict__ Whh0,
               const float* __restrict__ bih0, const float* __restrict__ bhh0,
               const float* __restrict__ Wih1, const float* __restrict__ Whh1,
               const float* __restrict__ bih1, const float* __restrict__ bhh1,
               const float* __restrict__ fcw, const float* __restrict__ fcb,
               float* __restrict__ out)
{
    const int t  = threadIdx.x;
    const int w  = t >> 6;          // wave 0..5
    const int j  = t & 63;          // lane
    const int s  = (w < 4) ? ((w & 1) ? 2 : 0) : 1;   // stage
    const int sw = (w < 4) ? (w >> 1) : (w & 1);      // dim half
    const int g  = j >> 1;          // local dim 0..31
    const int q  = j & 1;           // K-half
    const int d  = sw * 32 + g;     // dim 0..63
    const int b  = blockIdx.x;

    __shared__ __align__(16) float xs[TT * 2];       // 16 KB input
    __shared__ __align__(16) float h1b[2][HH];       // parity
    __shared__ __align__(16) float h2b[2][HH];       // parity
    __shared__ __align__(16) float4 xgb4[2][HH];     // parity, packed {r,z,n,-}
    __shared__ __align__(16) float fwS[HH];
    __shared__ int cnt[8];                           // soft-barrier counters
    __shared__ float ring[256][65];                  // h2 history (pads LDS >80KB
                                                     // on purpose: 1-block/CU target)

// spin until all 6 wave counters >= nd_ (acquire), lane-parallel single ds_read
#define WAITALL(nd_)                                                           \
    {                                                                          \
        const int need_ = (nd_);                                               \
        while (true) {                                                         \
            int c_ = (j < 6) ? __hip_atomic_load(&cnt[j], __ATOMIC_RELAXED,    \
                                   __HIP_MEMORY_SCOPE_WORKGROUP)               \
                             : 0x7fffffff;                                     \
            if (__all(c_ >= need_)) break;                                     \
            __builtin_amdgcn_s_sleep(1);                                       \
        }                                                                      \
        __threadfence_block();                                                 \
    }
// publish own counter (release)
#define PUBLISH(val_)                                                          \
    {                                                                          \
        __threadfence_block();                                                 \
        if (j == 0) __hip_atomic_store(&cnt[w], (val_), __ATOMIC_RELAXED,      \
                                       __HIP_MEMORY_SCOPE_WORKGROUP);          \
    }

    // ---- 96 weight floats as 48 named f2 (3 rows x 32 cols) ----
    const float* Wm = (s == 0) ? Whh0 : (s == 1) ? Wih1 : Whh1;
    const float4* P0 = (const float4*)(Wm + (size_t)(0 * HH + d) * HH + q * 32);
    const float4* P1 = (const float4*)(Wm + (size_t)(1 * HH + d) * HH + q * 32);
    const float4* P2 = (const float4*)(Wm + (size_t)(2 * HH + d) * HH + q * 32);
    f2 wa0, wa1, wa2, wa3, wa4, wa5, wa6, wa7,
       wa8, wa9, wa10, wa11, wa12, wa13, wa14, wa15;
    f2 wb0, wb1, wb2, wb3, wb4, wb5, wb6, wb7,
       wb8, wb9, wb10, wb11, wb12, wb13, wb14, wb15;
    f2 wc0, wc1, wc2, wc3, wc4, wc5, wc6, wc7,
       wc8, wc9, wc10, wc11, wc12, wc13, wc14, wc15;
    {
        float4 v;
        v = P0[0]; SPLIT(v, wa0,  wa1);  v = P0[1]; SPLIT(v, wa2,  wa3);
        v = P0[2]; SPLIT(v, wa4,  wa5);  v = P0[3]; SPLIT(v, wa6,  wa7);
        v = P0[4]; SPLIT(v, wa8,  wa9);  v = P0[5]; SPLIT(v, wa10, wa11);
        v = P0[6]; SPLIT(v, wa12, wa13); v = P0[7]; SPLIT(v, wa14, wa15);
        v = P1[0]; SPLIT(v, wb0,  wb1);  v = P1[1]; SPLIT(v, wb2,  wb3);
        v = P1[2]; SPLIT(v, wb4,  wb5);  v = P1[3]; SPLIT(v, wb6,  wb7);
        v = P1[4]; SPLIT(v, wb8,  wb9);  v = P1[5]; SPLIT(v, wb10, wb11);
        v = P1[6]; SPLIT(v, wb12, wb13); v = P1[7]; SPLIT(v, wb14, wb15);
        v = P2[0]; SPLIT(v, wc0,  wc1);  v = P2[1]; SPLIT(v, wc2,  wc3);
        v = P2[2]; SPLIT(v, wc4,  wc5);  v = P2[3]; SPLIT(v, wc6,  wc7);
        v = P2[4]; SPLIT(v, wc8,  wc9);  v = P2[5]; SPLIT(v, wc10, wc11);
        v = P2[6]; SPLIT(v, wc12, wc13); v = P2[7]; SPLIT(v, wc14, wc15);
    }
    PIN2(wa0);  PIN2(wa1);  PIN2(wa2);  PIN2(wa3);
    PIN2(wa4);  PIN2(wa5);  PIN2(wa6);  PIN2(wa7);
    PIN2(wa8);  PIN2(wa9);  PIN2(wa10); PIN2(wa11);
    PIN2(wa12); PIN2(wa13); PIN2(wa14); PIN2(wa15);
    PIN2(wb0);  PIN2(wb1);  PIN2(wb2);  PIN2(wb3);
    PIN2(wb4);  PIN2(wb5);  PIN2(wb6);  PIN2(wb7);
    PIN2(wb8);  PIN2(wb9);  PIN2(wb10); PIN2(wb11);
    PIN2(wb12); PIN2(wb13); PIN2(wb14); PIN2(wb15);
    PIN2(wc0);  PIN2(wc1);  PIN2(wc2);  PIN2(wc3);
    PIN2(wc4);  PIN2(wc5);  PIN2(wc6);  PIN2(wc7);
    PIN2(wc8);  PIN2(wc9);  PIN2(wc10); PIN2(wc11);
    PIN2(wc12); PIN2(wc13); PIN2(wc14); PIN2(wc15);

    // biases (added AFTER the reduce, so loaded once per lane)
    float kb0, kb1, kb2, bi2 = 0.f;
    if (s == 0) {            // r,z: fold bih0+bhh0; n: bhh0 inside r*(), bih0 outside
        kb0 = bhh0[d] + bih0[d];
        kb1 = bhh0[HH + d] + bih0[HH + d];
        kb2 = bhh0[2 * HH + d];
        bi2 = bih0[2 * HH + d];
    } else if (s == 1) {
        kb0 = bih1[d]; kb1 = bih1[HH + d]; kb2 = bih1[2 * HH + d];
    } else {
        kb0 = bhh1[d]; kb1 = bhh1[HH + d]; kb2 = bhh1[2 * HH + d];
    }
    float wi0 = 0, wi1 = 0, wi2 = 0, wi3 = 0, wi4 = 0, wi5 = 0;
    if (s == 0) {
        wi0 = Wih0[d * 2];            wi1 = Wih0[d * 2 + 1];
        wi2 = Wih0[(HH + d) * 2];     wi3 = Wih0[(HH + d) * 2 + 1];
        wi4 = Wih0[(2 * HH + d) * 2]; wi5 = Wih0[(2 * HH + d) * 2 + 1];
    }
    const float fcbv = fcb[0];

    // ---- preload x, zero state, init counters ----
    {
        const float4* xp  = (const float4*)(x + (size_t)b * TT * 2);
        float4*       xsp = (float4*)xs;
        for (int i2 = t; i2 < TT * 2 / 4; i2 += 384) xsp[i2] = xp[i2];
    }
    if (t < 2 * HH) { ((float*)h1b)[t] = 0.f; ((float*)h2b)[t] = 0.f; }
    if (t < HH) fwS[t] = fcw[t];
    if (t < 8) cnt[t] = -1;
    __syncthreads();    // one hard barrier: preload + counter init visible

    float hreg = 0.f;   // s0: h1[d]; s2: h2[d] (tracked redundantly by 2 lanes)

// One timestep. PC = IDX&1, PP = (IDX-1)&1 as literals; FL only in even steps.
#define STEP(IDX, PC, PP, FL)                                                  \
    {                                                                          \
        const int i_ = (IDX);                                                  \
        WAITALL(i_ - 1);                                                       \
        const bool act = (s == 0) ? (i_ < TT)                                  \
                       : (s == 1) ? (i_ >= 1 && i_ <= TT)                      \
                                  : (i_ >= 2);                                 \
        if (act) {                                                             \
            const float4* hp = ((const float4*)((s < 2) ? h1b[PP] : h2b[PP])) + q * 8; \
            f2 h0, h1, h2, h3, h4, h5, h6, h7,                                 \
               h8, h9, h10, h11, h12, h13, h14, h15;                           \
            {                                                                  \
                float4 v_;                                                     \
                v_ = hp[0]; SPLIT(v_, h0,  h1);  v_ = hp[1]; SPLIT(v_, h2,  h3); \
                v_ = hp[2]; SPLIT(v_, h4,  h5);  v_ = hp[3]; SPLIT(v_, h6,  h7); \
                v_ = hp[4]; SPLIT(v_, h8,  h9);  v_ = hp[5]; SPLIT(v_, h10, h11);\
                v_ = hp[6]; SPLIT(v_, h12, h13); v_ = hp[7]; SPLIT(v_, h14, h15);\
            }                                                                  \
            f2 aR = {0.f, 0.f}, aZ = {0.f, 0.f}, aN = {0.f, 0.f};              \
            PKFMA(aR, wa0,  h0);  PKFMA(aZ, wb0,  h0);  PKFMA(aN, wc0,  h0);   \
            PKFMA(aR, wa1,  h1);  PKFMA(aZ, wb1,  h1);  PKFMA(aN, wc1,  h1);   \
            PKFMA(aR, wa2,  h2);  PKFMA(aZ, wb2,  h2);  PKFMA(aN, wc2,  h2);   \
            PKFMA(aR, wa3,  h3);  PKFMA(aZ, wb3,  h3);  PKFMA(aN, wc3,  h3);   \
            PKFMA(aR, wa4,  h4);  PKFMA(aZ, wb4,  h4);  PKFMA(aN, wc4,  h4);   \
            PKFMA(aR, wa5,  h5);  PKFMA(aZ, wb5,  h5);  PKFMA(aN, wc5,  h5);   \
            PKFMA(aR, wa6,  h6);  PKFMA(aZ, wb6,  h6);  PKFMA(aN, wc6,  h6);   \
            PKFMA(aR, wa7,  h7);  PKFMA(aZ, wb7,  h7);  PKFMA(aN, wc7,  h7);   \
            PKFMA(aR, wa8,  h8);  PKFMA(aZ, wb8,  h8);  PKFMA(aN, wc8,  h8);   \
            PKFMA(aR, wa9,  h9);  PKFMA(aZ, wb9,  h9);  PKFMA(aN, wc9,  h9);   \
            PKFMA(aR, wa10, h10); PKFMA(aZ, wb10, h10); PKFMA(aN, wc10, h10);  \
            PKFMA(aR, wa11, h11); PKFMA(aZ, wb11, h11); PKFMA(aN, wc11, h11);  \
            PKFMA(aR, wa12, h12); PKFMA(aZ, wb12, h12); PKFMA(aN, wc12, h12);  \
            PKFMA(aR, wa13, h13); PKFMA(aZ, wb13, h13); PKFMA(aN, wc13, h13);  \
            PKFMA(aR, wa14, h14); PKFMA(aZ, wb14, h14); PKFMA(aN, wc14, h14);  \
            PKFMA(aR, wa15, h15); PKFMA(aZ, wb15, h15); PKFMA(aN, wc15, h15);  \
            float sr = aR.x + aR.y, sz = aZ.x + aZ.y, sn = aN.x + aN.y;        \
            sr = dppadd1(sr); sz = dppadd1(sz); sn = dppadd1(sn);              \
            sr += kb0; sz += kb1; sn += kb2;                                   \
            if (s == 0) {                                                      \
                f2 xv = *(const f2*)(xs + 2 * i_);                             \
                float rr = sigm (fmaf(wi0, xv.x, fmaf(wi1, xv.y, sr)));        \
                float zz = sigm (fmaf(wi2, xv.x, fmaf(wi3, xv.y, sz)));        \
                float nn = ftanh(fmaf(wi4, xv.x, fmaf(wi5, xv.y, bi2)) + rr * sn); \
                hreg = (1.f - zz) * nn + zz * hreg;                            \
                if (q == 0) h1b[PC][d] = hreg;                                 \
            } else if (s == 1) {                                               \
                if (q == 0) xgb4[PP][d] = make_float4(sr, sz, sn, 0.f);        \
            } else {                                                           \
                float4 xg = xgb4[PC][d];                                       \
                float rr = sigm (xg.x + sr);                                   \
                float zz = sigm (xg.y + sz);                                   \
                float nn = ftanh(xg.z + rr * sn);                              \
                hreg = (1.f - zz) * nn + zz * hreg;                            \
                if (q == 0) {                                                  \
                    h2b[PC][d] = hreg;                                         \
                    ring[(i_ - 2) & 255][d] = hreg;                            \
                }                                                              \
            }                                                                  \
        }                                                                      \
        if (FL && w == 3 && i_ >= 66 && ((i_ - 66) & 63) == 0) {               \
            const int tt = ((i_ - 66) >> 6) * 64 + j;                          \
            const float* rr2 = ring[tt & 255];                                 \
            float acc0 = 0.f, acc1 = 0.f;                                      \
            _Pragma("unroll")                                                  \
            for (int k = 0; k < 64; k += 2) {                                  \
                acc0 += rr2[k]     * fwS[k];                                   \
                acc1 += rr2[k + 1] * fwS[k + 1];                               \
            }                                                                  \
            out[(size_t)b * TT + tt] = acc0 + acc1 + fcbv;                     \
        }                                                                      \
        PUBLISH(i_);                                                           \
    }

    for (int ii = 0; ii < TT + 2; ii += 2) {
        STEP(ii,     0, 1, true);     // even step: parity (0,1), flush check
        STEP(ii + 1, 1, 0, false);    // odd  step: parity (1,0)
    }
#undef STEP

    __syncthreads();
    if (w == 3) {                                // final chunk: t = 1984..2047
        const int tt = 31 * 64 + j;
        const float* rr2 = ring[tt & 255];
        float acc0 = 0.f, acc1 = 0.f;
        #pragma unroll
        for (int k = 0; k < 64; k += 2) {
            acc0 += rr2[k]     * fwS[k];
            acc1 += rr2[k + 1] * fwS[k + 1];
        }
        out[(size_t)b * TT + tt] = acc0 + acc1 + fcbv;
    }
}

extern "C" void kernel_launch(void* const* d_in, const int* in_sizes, int n_in,
                              void* d_out, int out_size, void* d_ws, size_t ws_size,
                              hipStream_t stream) {
    const float* x    = (const float*)d_in[0];
    const float* Wih0 = (const float*)d_in[1];
    const float* Whh0 = (const float*)d_in[2];
    const float* bih0 = (const float*)d_in[3];
    const float* bhh0 = (const float*)d_in[4];
    const float* Wih1 = (const float*)d_in[5];
    const float* Whh1 = (const float*)d_in[6];
    const float* bih1 = (const float*)d_in[7];
    const float* bhh1 = (const float*)d_in[8];
    const float* fcw  = (const float*)d_in[9];
    const float* fcb  = (const float*)d_in[10];
    float* out = (float*)d_out;

    gru_fused<<<BB, 384, 0, stream>>>(x, Wih0, Whh0, bih0, bhh0,
                                      Wih1, Whh1, bih1, bhh1, fcw, fcb, out);
}